// Round 8
// baseline (460.549 us; speedup 1.0000x reference)
//
#include <hip/hip_runtime.h>
#include <hip/hip_bf16.h>

// GraphConv: out = verts@W0^T + b0 + scatter_sum_undirected(verts@W1^T + b1)
// V=100000, E=1000000, D=64. fp32 in/out; edges int64 (or int32) detected.
//
// R7 -> R8: matvec was ds_read-throughput-bound (128 ds_read_b32/vertex =
// 12.8M wave-instrs -> ~120 us). Now 8 vertices per wave share each weight
// read: 16 ds_read/vertex -> LDS ~15 us, VALU ~22 us. Fill col writes use
// nontemporal stores (scatter, no reuse).

#define NV 100000
#define NE 1000000
#define DIM 64
#define CAP 64
#define SPILL_MAX 65536

// ---------------------------------------------------------------------------
// Edge-layout detection. int64 words: [a_lo,a_hi,b_lo,b_hi,...], hi==0 always
// (0 <= idx < 100000). int32 words: [a0,b0,a1,b1,...], odd words random in
// [0,V). First 64 odd words all zero => int64 (FP prob ~ V^-64 ~ 0).
// ---------------------------------------------------------------------------
__global__ void detect_kernel(const int* __restrict__ edges, int* __restrict__ flag) {
    int v = edges[2 * threadIdx.x + 1];
    unsigned long long any = __ballot(v != 0);
    if (threadIdx.x == 0) *flag = (any == 0ull) ? 1 : 0;  // 1 = int64 layout
}

__device__ __forceinline__ unsigned f2bf1(float f) {  // RNE fp32 -> bf16 bits
    unsigned u = __float_as_uint(f);
    return (u + 0x7fffu + ((u >> 16) & 1u)) >> 16;
}

// verts (fp32) -> vbf (bf16-packed rows, 2 features per uint, 128 B/row)
__global__ void prep_kernel(const float* __restrict__ verts, uint2* __restrict__ vbf) {
    long i = (long)blockIdx.x * blockDim.x + threadIdx.x;   // one float4 each
    if (i < (long)NV * (DIM / 4)) {
        float4 v = ((const float4*)verts)[i];
        uint2 w;
        w.x = f2bf1(v.x) | (f2bf1(v.y) << 16);
        w.y = f2bf1(v.z) | (f2bf1(v.w) << 16);
        vbf[i] = w;
    }
}

__device__ __forceinline__ void push_edge(int t, int n, int* cnt, int* col,
                                          int* spill, int* nspill) {
    int p = atomicAdd(&cnt[t], 1);
    if (p < CAP) {
        __builtin_nontemporal_store(n, &col[t * CAP + p]);  // scatter, no reuse
    } else {
        int sp = atomicAdd(nspill, 1);
        if (sp < SPILL_MAX) { spill[2 * sp] = t; spill[2 * sp + 1] = n; }
    }
}

__global__ void fill_kernel(const int* __restrict__ edges,
                            int* __restrict__ cnt, int* __restrict__ col,
                            int* __restrict__ spill, int* __restrict__ nspill,
                            const int* __restrict__ flag) {
    const bool is64 = (*flag != 0);
    const long stride = (long)gridDim.x * blockDim.x;
    for (long e = (long)blockIdx.x * blockDim.x + threadIdx.x; e < NE; e += stride) {
        int a, b;
        if (is64) { int4 q = ((const int4*)edges)[e]; a = q.x; b = q.z; }
        else      { int2 q = ((const int2*)edges)[e]; a = q.x; b = q.y; }
        push_edge(a, b, cnt, col, spill, nspill);
        push_edge(b, a, cnt, col, spill, nspill);
    }
}

__device__ __forceinline__ void acc4(float4& a, uint2 w) {
    a.x += __uint_as_float(w.x << 16);
    a.y += __uint_as_float(w.x & 0xffff0000u);
    a.z += __uint_as_float(w.y << 16);
    a.w += __uint_as_float(w.y & 0xffff0000u);
}

// One wave per vertex. Lane = (group 0..3, sub 0..15); group g gathers rows
// j+g, j+g+4, j+g+8, j+g+12 each iteration (16 rows in flight/wave).
// ALL shfls execute under full, converged exec (R6 fix).
__global__ __launch_bounds__(256)
void gather_kernel(const uint2* __restrict__ vbf, const int* __restrict__ cnt,
                   const int* __restrict__ col, float* __restrict__ sums) {
    const int lane = threadIdx.x & 63;
    const int sub = lane & 15;
    const int grp = lane >> 4;
    const int v = (int)((blockIdx.x * blockDim.x + threadIdx.x) >> 6);
    if (v >= NV) return;                 // wave-uniform

    int dg = cnt[v]; if (dg > CAP) dg = CAP;   // wave-uniform
    const int myc = col[v * CAP + lane];       // whole CAP row, 1 load

    float4 a0 = {0.f, 0.f, 0.f, 0.f}, a1 = a0, a2 = a0, a3 = a0;
    int j = 0;
    for (; j + 16 <= dg; j += 16) {            // uniform bound: no divergence
        const int i0 = j + grp;
        const int c0 = __shfl(myc, i0, 64);
        const int c1 = __shfl(myc, i0 + 4, 64);
        const int c2 = __shfl(myc, i0 + 8, 64);
        const int c3 = __shfl(myc, i0 + 12, 64);
        const uint2 w0 = vbf[(long)c0 * 16 + sub];
        const uint2 w1 = vbf[(long)c1 * 16 + sub];
        const uint2 w2 = vbf[(long)c2 * 16 + sub];
        const uint2 w3 = vbf[(long)c3 * 16 + sub];
        acc4(a0, w0); acc4(a1, w1); acc4(a2, w2); acc4(a3, w3);
    }
#pragma unroll
    for (int t = 0; t < 4; ++t) {              // tail: shfl unconditional
        const int ii = j + grp + 4 * t;
        const int c = __shfl(myc, ii < 63 ? ii : 63, 64);
        if (ii < dg) acc4(a0, vbf[(long)c * 16 + sub]);
    }

    a0.x += (a1.x + a2.x) + a3.x;
    a0.y += (a1.y + a2.y) + a3.y;
    a0.z += (a1.z + a2.z) + a3.z;
    a0.w += (a1.w + a2.w) + a3.w;
    a0.x += __shfl_xor(a0.x, 16, 64); a0.y += __shfl_xor(a0.y, 16, 64);
    a0.z += __shfl_xor(a0.z, 16, 64); a0.w += __shfl_xor(a0.w, 16, 64);
    a0.x += __shfl_xor(a0.x, 32, 64); a0.y += __shfl_xor(a0.y, 32, 64);
    a0.z += __shfl_xor(a0.z, 32, 64); a0.w += __shfl_xor(a0.w, 32, 64);

    if (lane < 16) ((float4*)(sums + (long)v * DIM))[sub] = a0;
}

// Rare path: overflow edges (deg > CAP) — adds fp32 rows into sums.
__global__ void spill_kernel(const float* __restrict__ verts,
                             const int* __restrict__ spill,
                             const int* __restrict__ nspill,
                             float* __restrict__ sums) {
    const int lane = threadIdx.x & 63;
    const int wave = (int)((blockIdx.x * blockDim.x + threadIdx.x) >> 6);
    const int nwaves = (int)((gridDim.x * blockDim.x) >> 6);
    int n = *nspill; if (n > SPILL_MAX) n = SPILL_MAX;
    for (int i = wave; i < n; i += nwaves) {
        const int t = spill[2 * i], nb = spill[2 * i + 1];
        atomicAdd(&sums[(long)t * DIM + lane], verts[(long)nb * DIM + lane]);
    }
}

// ---------------------------------------------------------------------------
// out[v,:] = W0 x_v + b0 + W1 s_v + deg_v * b1.
// 8 vertices per wave: each LDS weight read (w0T[k*64+lane], lane-stride-1,
// conflict-free) is reused by 8 FMA chains -> 16 ds_read/vertex instead of
// 128. x/s broadcast via __shfl with unroll-constant k (v_readlane).
// NV = 100000 = 12500 octets exactly; grid 3125 blocks x 4 waves, no bounds.
// ---------------------------------------------------------------------------
__global__ __launch_bounds__(256)
void matvec8_kernel(const float* __restrict__ verts,
                    const float* __restrict__ w0,
                    const float* __restrict__ b0,
                    const float* __restrict__ w1,
                    const float* __restrict__ b1,
                    const float* __restrict__ sums,
                    const int* __restrict__ cnt,
                    float* __restrict__ out) {
    __shared__ float w0T[DIM * DIM];   // 16 KB: w0T[k*64+d] = w0[d*64+k]
    __shared__ float w1T[DIM * DIM];   // 16 KB

    for (int i = threadIdx.x; i < DIM * DIM; i += 256) {
        const int k = i >> 6, d = i & 63;
        w0T[i] = w0[d * DIM + k];
        w1T[i] = w1[d * DIM + k];
    }
    __syncthreads();

    const int lane = threadIdx.x & 63;
    const int wave = (int)((blockIdx.x * blockDim.x + threadIdx.x) >> 6);
    const long base = (long)wave * 8;                 // 12500 waves exactly
    const float bias0 = b0[lane];
    const float bias1 = b1[lane];

    float x0 = verts[(base + 0) * DIM + lane], s0 = sums[(base + 0) * DIM + lane];
    float x1 = verts[(base + 1) * DIM + lane], s1 = sums[(base + 1) * DIM + lane];
    float x2 = verts[(base + 2) * DIM + lane], s2 = sums[(base + 2) * DIM + lane];
    float x3 = verts[(base + 3) * DIM + lane], s3 = sums[(base + 3) * DIM + lane];
    float x4 = verts[(base + 4) * DIM + lane], s4 = sums[(base + 4) * DIM + lane];
    float x5 = verts[(base + 5) * DIM + lane], s5 = sums[(base + 5) * DIM + lane];
    float x6 = verts[(base + 6) * DIM + lane], s6 = sums[(base + 6) * DIM + lane];
    float x7 = verts[(base + 7) * DIM + lane], s7 = sums[(base + 7) * DIM + lane];

    float y0 = fmaf((float)cnt[base + 0], bias1, bias0);
    float y1 = fmaf((float)cnt[base + 1], bias1, bias0);
    float y2 = fmaf((float)cnt[base + 2], bias1, bias0);
    float y3 = fmaf((float)cnt[base + 3], bias1, bias0);
    float y4 = fmaf((float)cnt[base + 4], bias1, bias0);
    float y5 = fmaf((float)cnt[base + 5], bias1, bias0);
    float y6 = fmaf((float)cnt[base + 6], bias1, bias0);
    float y7 = fmaf((float)cnt[base + 7], bias1, bias0);

#pragma unroll
    for (int k = 0; k < DIM; ++k) {
        const float wk0 = w0T[k * DIM + lane];
        const float wk1 = w1T[k * DIM + lane];
        y0 = fmaf(__shfl(x0, k, 64), wk0, y0); y0 = fmaf(__shfl(s0, k, 64), wk1, y0);
        y1 = fmaf(__shfl(x1, k, 64), wk0, y1); y1 = fmaf(__shfl(s1, k, 64), wk1, y1);
        y2 = fmaf(__shfl(x2, k, 64), wk0, y2); y2 = fmaf(__shfl(s2, k, 64), wk1, y2);
        y3 = fmaf(__shfl(x3, k, 64), wk0, y3); y3 = fmaf(__shfl(s3, k, 64), wk1, y3);
        y4 = fmaf(__shfl(x4, k, 64), wk0, y4); y4 = fmaf(__shfl(s4, k, 64), wk1, y4);
        y5 = fmaf(__shfl(x5, k, 64), wk0, y5); y5 = fmaf(__shfl(s5, k, 64), wk1, y5);
        y6 = fmaf(__shfl(x6, k, 64), wk0, y6); y6 = fmaf(__shfl(s6, k, 64), wk1, y6);
        y7 = fmaf(__shfl(x7, k, 64), wk0, y7); y7 = fmaf(__shfl(s7, k, 64), wk1, y7);
    }

    out[(base + 0) * DIM + lane] = y0;
    out[(base + 1) * DIM + lane] = y1;
    out[(base + 2) * DIM + lane] = y2;
    out[(base + 3) * DIM + lane] = y3;
    out[(base + 4) * DIM + lane] = y4;
    out[(base + 5) * DIM + lane] = y5;
    out[(base + 6) * DIM + lane] = y6;
    out[(base + 7) * DIM + lane] = y7;
}

// ==========================================================================

extern "C" void kernel_launch(void* const* d_in, const int* in_sizes, int n_in,
                              void* d_out, int out_size, void* d_ws, size_t ws_size,
                              hipStream_t stream) {
    const float* verts = (const float*)d_in[0];
    const int*   edges = (const int*)d_in[1];
    const float* w0_w  = (const float*)d_in[2];
    const float* w0_b  = (const float*)d_in[3];
    const float* w1_w  = (const float*)d_in[4];
    const float* w1_b  = (const float*)d_in[5];
    float* out = (float*)d_out;

    // Workspace: sums fp32 V*D | vbf bf16 V*D | col V*CAP | spill | cnt | misc
    char* p = (char*)d_ws;
    float* sums  = (float*)p;  p += (size_t)NV * DIM * 4;
    uint2* vbf   = (uint2*)p;  p += (size_t)NV * DIM * 2;
    int* col     = (int*)p;    p += (size_t)NV * CAP * 4;
    int* spill   = (int*)p;    p += (size_t)SPILL_MAX * 8;
    int* cnt     = (int*)p;    p += (size_t)NV * 4;
    int* nspill  = (int*)p;
    int* flag    = nspill + 1;

    hipMemsetAsync(cnt, 0, (size_t)NV * 4 + 8, stream);
    detect_kernel<<<1, 64, 0, stream>>>(edges, flag);
    prep_kernel<<<(NV * (DIM / 4) + 255) / 256, 256, 0, stream>>>(verts, vbf);
    fill_kernel<<<2048, 256, 0, stream>>>(edges, cnt, col, spill, nspill, flag);
    gather_kernel<<<(NV + 3) / 4, 256, 0, stream>>>(vbf, cnt, col, sums);
    spill_kernel<<<64, 256, 0, stream>>>(verts, spill, nspill, sums);
    // 12500 waves = 3125 blocks, one 8-vertex octet per wave (100000 = 8*12500)
    matvec8_kernel<<<3125, 256, 0, stream>>>(verts, w0_w, w0_b, w1_w, w1_b,
                                             sums, cnt, out);
}

// Round 9
// 374.526 us; speedup vs baseline: 1.2297x; 1.2297x over previous
//
#include <hip/hip_runtime.h>
#include <hip/hip_bf16.h>

// GraphConv: out = verts@W0^T + b0 + scatter_sum_undirected(verts@W1^T + b1)
// V=100000, E=1000000, D=64. fp32 in/out; edges int64 (or int32) detected.
//
// R8 -> R9: fill was bound by scattered 4B col writes turning into 2M x 64B
// partial-line evictions (WRITE 123MB @ 0.73TB/s = the whole 178us): col
// lines were touched from all 8 XCDs, so no per-XCD L2 write-combining.
// Now fill is XCD-range-partitioned: block b (xcd = b&7) only pushes
// endpoints in [xcd*12500,(xcd+1)*12500); each cnt/col line is owned by one
// XCD and its 3.2MB partition fits the 4MB per-XCD L2. Edges read 8x (L3-
// resident). Also reverted R8's nontemporal col stores (defeated combining).

#define NV 100000
#define NE 1000000
#define DIM 64
#define CAP 64
#define SPILL_MAX 65536
#define NXCD 8
#define VPERX ((NV + NXCD - 1) / NXCD)   // 12500 vertices per XCD partition

// ---------------------------------------------------------------------------
// Edge-layout detection. int64 words: [a_lo,a_hi,b_lo,b_hi,...], hi==0 always
// (0 <= idx < 100000). int32 words: [a0,b0,a1,b1,...], odd words random in
// [0,V). First 64 odd words all zero => int64 (FP prob ~ V^-64 ~ 0).
// ---------------------------------------------------------------------------
__global__ void detect_kernel(const int* __restrict__ edges, int* __restrict__ flag) {
    int v = edges[2 * threadIdx.x + 1];
    unsigned long long any = __ballot(v != 0);
    if (threadIdx.x == 0) *flag = (any == 0ull) ? 1 : 0;  // 1 = int64 layout
}

__device__ __forceinline__ unsigned f2bf1(float f) {  // RNE fp32 -> bf16 bits
    unsigned u = __float_as_uint(f);
    return (u + 0x7fffu + ((u >> 16) & 1u)) >> 16;
}

// verts (fp32) -> vbf (bf16-packed rows, 2 features per uint, 128 B/row)
__global__ void prep_kernel(const float* __restrict__ verts, uint2* __restrict__ vbf) {
    long i = (long)blockIdx.x * blockDim.x + threadIdx.x;   // one float4 each
    if (i < (long)NV * (DIM / 4)) {
        float4 v = ((const float4*)verts)[i];
        uint2 w;
        w.x = f2bf1(v.x) | (f2bf1(v.y) << 16);
        w.y = f2bf1(v.z) | (f2bf1(v.w) << 16);
        vbf[i] = w;
    }
}

__device__ __forceinline__ void push_edge(int t, int n, int* cnt, int* col,
                                          int* spill, int* nspill) {
    int p = atomicAdd(&cnt[t], 1);
    if (p < CAP) {
        col[t * CAP + p] = n;              // plain store: L2 write-combining
    } else {
        int sp = atomicAdd(nspill, 1);
        if (sp < SPILL_MAX) { spill[2 * sp] = t; spill[2 * sp + 1] = n; }
    }
}

// XCD-partitioned fill: block b serves partition xcd = b & 7; the 256-block
// sub-grid {b : b&7 == xcd} grid-strides over ALL edges and pushes only
// endpoints belonging to its vertex range. Correct for any block placement;
// fast when blocks round-robin across XCDs (cnt/col lines become XCD-local).
__global__ void fill_kernel(const int* __restrict__ edges,
                            int* __restrict__ cnt, int* __restrict__ col,
                            int* __restrict__ spill, int* __restrict__ nspill,
                            const int* __restrict__ flag) {
    const bool is64 = (*flag != 0);
    const int xcd = blockIdx.x & (NXCD - 1);
    const int sub = blockIdx.x >> 3;                   // 0..255
    const int nsub = gridDim.x >> 3;
    const int vlo = xcd * VPERX;
    const int vhi = vlo + VPERX;                       // [vlo, vhi)
    const long stride = (long)nsub * blockDim.x;

    for (long e = (long)sub * blockDim.x + threadIdx.x; e < NE; e += stride) {
        int a, b;
        if (is64) { int4 q = ((const int4*)edges)[e]; a = q.x; b = q.z; }
        else      { int2 q = ((const int2*)edges)[e]; a = q.x; b = q.y; }
        if (a >= vlo && a < vhi) push_edge(a, b, cnt, col, spill, nspill);
        if (b >= vlo && b < vhi) push_edge(b, a, cnt, col, spill, nspill);
    }
}

__device__ __forceinline__ void acc4(float4& a, uint2 w) {
    a.x += __uint_as_float(w.x << 16);
    a.y += __uint_as_float(w.x & 0xffff0000u);
    a.z += __uint_as_float(w.y << 16);
    a.w += __uint_as_float(w.y & 0xffff0000u);
}

// One wave per vertex. Lane = (group 0..3, sub 0..15); group g gathers rows
// j+g, j+g+4, j+g+8, j+g+12 each iteration (16 rows in flight/wave).
// ALL shfls execute under full, converged exec (R6 fix).
__global__ __launch_bounds__(256)
void gather_kernel(const uint2* __restrict__ vbf, const int* __restrict__ cnt,
                   const int* __restrict__ col, float* __restrict__ sums) {
    const int lane = threadIdx.x & 63;
    const int sub = lane & 15;
    const int grp = lane >> 4;
    const int v = (int)((blockIdx.x * blockDim.x + threadIdx.x) >> 6);
    if (v >= NV) return;                 // wave-uniform

    int dg = cnt[v]; if (dg > CAP) dg = CAP;   // wave-uniform
    const int myc = col[v * CAP + lane];       // whole CAP row, 1 load

    float4 a0 = {0.f, 0.f, 0.f, 0.f}, a1 = a0, a2 = a0, a3 = a0;
    int j = 0;
    for (; j + 16 <= dg; j += 16) {            // uniform bound: no divergence
        const int i0 = j + grp;
        const int c0 = __shfl(myc, i0, 64);
        const int c1 = __shfl(myc, i0 + 4, 64);
        const int c2 = __shfl(myc, i0 + 8, 64);
        const int c3 = __shfl(myc, i0 + 12, 64);
        const uint2 w0 = vbf[(long)c0 * 16 + sub];
        const uint2 w1 = vbf[(long)c1 * 16 + sub];
        const uint2 w2 = vbf[(long)c2 * 16 + sub];
        const uint2 w3 = vbf[(long)c3 * 16 + sub];
        acc4(a0, w0); acc4(a1, w1); acc4(a2, w2); acc4(a3, w3);
    }
#pragma unroll
    for (int t = 0; t < 4; ++t) {              // tail: shfl unconditional
        const int ii = j + grp + 4 * t;
        const int c = __shfl(myc, ii < 63 ? ii : 63, 64);
        if (ii < dg) acc4(a0, vbf[(long)c * 16 + sub]);
    }

    a0.x += (a1.x + a2.x) + a3.x;
    a0.y += (a1.y + a2.y) + a3.y;
    a0.z += (a1.z + a2.z) + a3.z;
    a0.w += (a1.w + a2.w) + a3.w;
    a0.x += __shfl_xor(a0.x, 16, 64); a0.y += __shfl_xor(a0.y, 16, 64);
    a0.z += __shfl_xor(a0.z, 16, 64); a0.w += __shfl_xor(a0.w, 16, 64);
    a0.x += __shfl_xor(a0.x, 32, 64); a0.y += __shfl_xor(a0.y, 32, 64);
    a0.z += __shfl_xor(a0.z, 32, 64); a0.w += __shfl_xor(a0.w, 32, 64);

    if (lane < 16) ((float4*)(sums + (long)v * DIM))[sub] = a0;
}

// Rare path: overflow edges (deg > CAP) — adds fp32 rows into sums.
__global__ void spill_kernel(const float* __restrict__ verts,
                             const int* __restrict__ spill,
                             const int* __restrict__ nspill,
                             float* __restrict__ sums) {
    const int lane = threadIdx.x & 63;
    const int wave = (int)((blockIdx.x * blockDim.x + threadIdx.x) >> 6);
    const int nwaves = (int)((gridDim.x * blockDim.x) >> 6);
    int n = *nspill; if (n > SPILL_MAX) n = SPILL_MAX;
    for (int i = wave; i < n; i += nwaves) {
        const int t = spill[2 * i], nb = spill[2 * i + 1];
        atomicAdd(&sums[(long)t * DIM + lane], verts[(long)nb * DIM + lane]);
    }
}

// ---------------------------------------------------------------------------
// out[v,:] = W0 x_v + b0 + W1 s_v + deg_v * b1.
// 8 vertices per wave: each LDS weight read (lane-stride-1, conflict-free)
// is reused by 8 FMA chains -> 16 ds_read/vertex. x/s broadcast via __shfl
// with unroll-constant k (v_readlane). 100000 = 8 * 12500 waves exactly.
// ---------------------------------------------------------------------------
__global__ __launch_bounds__(256)
void matvec8_kernel(const float* __restrict__ verts,
                    const float* __restrict__ w0,
                    const float* __restrict__ b0,
                    const float* __restrict__ w1,
                    const float* __restrict__ b1,
                    const float* __restrict__ sums,
                    const int* __restrict__ cnt,
                    float* __restrict__ out) {
    __shared__ float w0T[DIM * DIM];   // 16 KB: w0T[k*64+d] = w0[d*64+k]
    __shared__ float w1T[DIM * DIM];   // 16 KB

    for (int i = threadIdx.x; i < DIM * DIM; i += 256) {
        const int k = i >> 6, d = i & 63;
        w0T[i] = w0[d * DIM + k];
        w1T[i] = w1[d * DIM + k];
    }
    __syncthreads();

    const int lane = threadIdx.x & 63;
    const int wave = (int)((blockIdx.x * blockDim.x + threadIdx.x) >> 6);
    const long base = (long)wave * 8;                 // 12500 waves exactly
    const float bias0 = b0[lane];
    const float bias1 = b1[lane];

    float x0 = verts[(base + 0) * DIM + lane], s0 = sums[(base + 0) * DIM + lane];
    float x1 = verts[(base + 1) * DIM + lane], s1 = sums[(base + 1) * DIM + lane];
    float x2 = verts[(base + 2) * DIM + lane], s2 = sums[(base + 2) * DIM + lane];
    float x3 = verts[(base + 3) * DIM + lane], s3 = sums[(base + 3) * DIM + lane];
    float x4 = verts[(base + 4) * DIM + lane], s4 = sums[(base + 4) * DIM + lane];
    float x5 = verts[(base + 5) * DIM + lane], s5 = sums[(base + 5) * DIM + lane];
    float x6 = verts[(base + 6) * DIM + lane], s6 = sums[(base + 6) * DIM + lane];
    float x7 = verts[(base + 7) * DIM + lane], s7 = sums[(base + 7) * DIM + lane];

    float y0 = fmaf((float)cnt[base + 0], bias1, bias0);
    float y1 = fmaf((float)cnt[base + 1], bias1, bias0);
    float y2 = fmaf((float)cnt[base + 2], bias1, bias0);
    float y3 = fmaf((float)cnt[base + 3], bias1, bias0);
    float y4 = fmaf((float)cnt[base + 4], bias1, bias0);
    float y5 = fmaf((float)cnt[base + 5], bias1, bias0);
    float y6 = fmaf((float)cnt[base + 6], bias1, bias0);
    float y7 = fmaf((float)cnt[base + 7], bias1, bias0);

#pragma unroll
    for (int k = 0; k < DIM; ++k) {
        const float wk0 = w0T[k * DIM + lane];
        const float wk1 = w1T[k * DIM + lane];
        y0 = fmaf(__shfl(x0, k, 64), wk0, y0); y0 = fmaf(__shfl(s0, k, 64), wk1, y0);
        y1 = fmaf(__shfl(x1, k, 64), wk0, y1); y1 = fmaf(__shfl(s1, k, 64), wk1, y1);
        y2 = fmaf(__shfl(x2, k, 64), wk0, y2); y2 = fmaf(__shfl(s2, k, 64), wk1, y2);
        y3 = fmaf(__shfl(x3, k, 64), wk0, y3); y3 = fmaf(__shfl(s3, k, 64), wk1, y3);
        y4 = fmaf(__shfl(x4, k, 64), wk0, y4); y4 = fmaf(__shfl(s4, k, 64), wk1, y4);
        y5 = fmaf(__shfl(x5, k, 64), wk0, y5); y5 = fmaf(__shfl(s5, k, 64), wk1, y5);
        y6 = fmaf(__shfl(x6, k, 64), wk0, y6); y6 = fmaf(__shfl(s6, k, 64), wk1, y6);
        y7 = fmaf(__shfl(x7, k, 64), wk0, y7); y7 = fmaf(__shfl(s7, k, 64), wk1, y7);
    }

    out[(base + 0) * DIM + lane] = y0;
    out[(base + 1) * DIM + lane] = y1;
    out[(base + 2) * DIM + lane] = y2;
    out[(base + 3) * DIM + lane] = y3;
    out[(base + 4) * DIM + lane] = y4;
    out[(base + 5) * DIM + lane] = y5;
    out[(base + 6) * DIM + lane] = y6;
    out[(base + 7) * DIM + lane] = y7;
}

// ==========================================================================

extern "C" void kernel_launch(void* const* d_in, const int* in_sizes, int n_in,
                              void* d_out, int out_size, void* d_ws, size_t ws_size,
                              hipStream_t stream) {
    const float* verts = (const float*)d_in[0];
    const int*   edges = (const int*)d_in[1];
    const float* w0_w  = (const float*)d_in[2];
    const float* w0_b  = (const float*)d_in[3];
    const float* w1_w  = (const float*)d_in[4];
    const float* w1_b  = (const float*)d_in[5];
    float* out = (float*)d_out;

    // Workspace: sums fp32 V*D | vbf bf16 V*D | col V*CAP | spill | cnt | misc
    char* p = (char*)d_ws;
    float* sums  = (float*)p;  p += (size_t)NV * DIM * 4;
    uint2* vbf   = (uint2*)p;  p += (size_t)NV * DIM * 2;
    int* col     = (int*)p;    p += (size_t)NV * CAP * 4;
    int* spill   = (int*)p;    p += (size_t)SPILL_MAX * 8;
    int* cnt     = (int*)p;    p += (size_t)NV * 4;
    int* nspill  = (int*)p;
    int* flag    = nspill + 1;

    hipMemsetAsync(cnt, 0, (size_t)NV * 4 + 8, stream);
    detect_kernel<<<1, 64, 0, stream>>>(edges, flag);
    prep_kernel<<<(NV * (DIM / 4) + 255) / 256, 256, 0, stream>>>(verts, vbf);
    // 2048 blocks = 8 partitions x 256-block sub-grids
    fill_kernel<<<2048, 256, 0, stream>>>(edges, cnt, col, spill, nspill, flag);
    gather_kernel<<<(NV + 3) / 4, 256, 0, stream>>>(vbf, cnt, col, sums);
    spill_kernel<<<64, 256, 0, stream>>>(verts, spill, nspill, sums);
    // 12500 waves = 3125 blocks, one 8-vertex octet per wave
    matvec8_kernel<<<3125, 256, 0, stream>>>(verts, w0_w, w0_b, w1_w, w1_b,
                                             sums, cnt, out);
}

// Round 10
// 253.923 us; speedup vs baseline: 1.8137x; 1.4750x over previous
//
#include <hip/hip_runtime.h>
#include <hip/hip_bf16.h>

// GraphConv: out = verts@W0^T + b0 + scatter_sum_undirected(verts@W1^T + b1)
// V=100000, E=1000000, D=64. fp32 in/out; edges int64 (or int32) detected.
//
// R9 -> R10: matvec8 was shfl-bound (128 ds_bpermute/vertex = 26M wave-instrs
// -> 164 us, VALU 15%, HBM 4%). Replaced with MFMA: out = [X|S]@[W0;W1]^T as
// 16x16x32 bf16 MFMA, one wave per 16-vertex tile, B-frags (weights) hoisted.
// A chunks 0-1 read the existing bf16 vbf rows directly; chunks 2-3 pack fp32
// sums to bf16 in-flight. C/D layout: col=lane&15, row=quad*4+reg (verified);
// A: m=lane&15, k=quad*8+j; B mirrors A with n=lane&15.

#define NV 100000
#define NE 1000000
#define DIM 64
#define CAP 64
#define SPILL_MAX 65536
#define NXCD 8
#define VPERX ((NV + NXCD - 1) / NXCD)   // 12500 vertices per XCD partition
#define NTILE (NV / 16)                  // 6250 MFMA row-tiles exactly

typedef __attribute__((ext_vector_type(8))) short short8;   // 8 bf16
typedef __attribute__((ext_vector_type(4))) float f32x4;

// ---------------------------------------------------------------------------
// Edge-layout detection. int64 words: [a_lo,a_hi,b_lo,b_hi,...], hi==0 always
// (0 <= idx < 100000). int32 words: [a0,b0,a1,b1,...], odd words random in
// [0,V). First 64 odd words all zero => int64 (FP prob ~ V^-64 ~ 0).
// ---------------------------------------------------------------------------
__global__ void detect_kernel(const int* __restrict__ edges, int* __restrict__ flag) {
    int v = edges[2 * threadIdx.x + 1];
    unsigned long long any = __ballot(v != 0);
    if (threadIdx.x == 0) *flag = (any == 0ull) ? 1 : 0;  // 1 = int64 layout
}

__device__ __forceinline__ unsigned f2bf1(float f) {  // RNE fp32 -> bf16 bits
    unsigned u = __float_as_uint(f);
    return (u + 0x7fffu + ((u >> 16) & 1u)) >> 16;
}

__device__ __forceinline__ short8 pack_bf8(float4 a, float4 b) {
    short8 r;
    r[0] = (short)f2bf1(a.x); r[1] = (short)f2bf1(a.y);
    r[2] = (short)f2bf1(a.z); r[3] = (short)f2bf1(a.w);
    r[4] = (short)f2bf1(b.x); r[5] = (short)f2bf1(b.y);
    r[6] = (short)f2bf1(b.z); r[7] = (short)f2bf1(b.w);
    return r;
}

// verts (fp32) -> vbf (bf16-packed rows, 2 features per uint, 128 B/row)
__global__ void prep_kernel(const float* __restrict__ verts, uint2* __restrict__ vbf) {
    long i = (long)blockIdx.x * blockDim.x + threadIdx.x;   // one float4 each
    if (i < (long)NV * (DIM / 4)) {
        float4 v = ((const float4*)verts)[i];
        uint2 w;
        w.x = f2bf1(v.x) | (f2bf1(v.y) << 16);
        w.y = f2bf1(v.z) | (f2bf1(v.w) << 16);
        vbf[i] = w;
    }
}

__device__ __forceinline__ void push_edge(int t, int n, int* cnt, int* col,
                                          int* spill, int* nspill) {
    int p = atomicAdd(&cnt[t], 1);
    if (p < CAP) {
        col[t * CAP + p] = n;              // plain store: L2 write-combining
    } else {
        int sp = atomicAdd(nspill, 1);
        if (sp < SPILL_MAX) { spill[2 * sp] = t; spill[2 * sp + 1] = n; }
    }
}

// XCD-partitioned fill (R9): block b serves partition xcd = b & 7; each
// cnt/col line is owned by one XCD; its 3.2MB partition fits the 4MB L2.
__global__ void fill_kernel(const int* __restrict__ edges,
                            int* __restrict__ cnt, int* __restrict__ col,
                            int* __restrict__ spill, int* __restrict__ nspill,
                            const int* __restrict__ flag) {
    const bool is64 = (*flag != 0);
    const int xcd = blockIdx.x & (NXCD - 1);
    const int sub = blockIdx.x >> 3;
    const int nsub = gridDim.x >> 3;
    const int vlo = xcd * VPERX;
    const int vhi = vlo + VPERX;
    const long stride = (long)nsub * blockDim.x;

    for (long e = (long)sub * blockDim.x + threadIdx.x; e < NE; e += stride) {
        int a, b;
        if (is64) { int4 q = ((const int4*)edges)[e]; a = q.x; b = q.z; }
        else      { int2 q = ((const int2*)edges)[e]; a = q.x; b = q.y; }
        if (a >= vlo && a < vhi) push_edge(a, b, cnt, col, spill, nspill);
        if (b >= vlo && b < vhi) push_edge(b, a, cnt, col, spill, nspill);
    }
}

__device__ __forceinline__ void acc4(float4& a, uint2 w) {
    a.x += __uint_as_float(w.x << 16);
    a.y += __uint_as_float(w.x & 0xffff0000u);
    a.z += __uint_as_float(w.y << 16);
    a.w += __uint_as_float(w.y & 0xffff0000u);
}

// One wave per vertex; 16 rows in flight (R6-fixed: no shfl under divergence).
__global__ __launch_bounds__(256)
void gather_kernel(const uint2* __restrict__ vbf, const int* __restrict__ cnt,
                   const int* __restrict__ col, float* __restrict__ sums) {
    const int lane = threadIdx.x & 63;
    const int sub = lane & 15;
    const int grp = lane >> 4;
    const int v = (int)((blockIdx.x * blockDim.x + threadIdx.x) >> 6);
    if (v >= NV) return;

    int dg = cnt[v]; if (dg > CAP) dg = CAP;
    const int myc = col[v * CAP + lane];

    float4 a0 = {0.f, 0.f, 0.f, 0.f}, a1 = a0, a2 = a0, a3 = a0;
    int j = 0;
    for (; j + 16 <= dg; j += 16) {
        const int i0 = j + grp;
        const int c0 = __shfl(myc, i0, 64);
        const int c1 = __shfl(myc, i0 + 4, 64);
        const int c2 = __shfl(myc, i0 + 8, 64);
        const int c3 = __shfl(myc, i0 + 12, 64);
        const uint2 w0 = vbf[(long)c0 * 16 + sub];
        const uint2 w1 = vbf[(long)c1 * 16 + sub];
        const uint2 w2 = vbf[(long)c2 * 16 + sub];
        const uint2 w3 = vbf[(long)c3 * 16 + sub];
        acc4(a0, w0); acc4(a1, w1); acc4(a2, w2); acc4(a3, w3);
    }
#pragma unroll
    for (int t = 0; t < 4; ++t) {
        const int ii = j + grp + 4 * t;
        const int c = __shfl(myc, ii < 63 ? ii : 63, 64);
        if (ii < dg) acc4(a0, vbf[(long)c * 16 + sub]);
    }

    a0.x += (a1.x + a2.x) + a3.x;
    a0.y += (a1.y + a2.y) + a3.y;
    a0.z += (a1.z + a2.z) + a3.z;
    a0.w += (a1.w + a2.w) + a3.w;
    a0.x += __shfl_xor(a0.x, 16, 64); a0.y += __shfl_xor(a0.y, 16, 64);
    a0.z += __shfl_xor(a0.z, 16, 64); a0.w += __shfl_xor(a0.w, 16, 64);
    a0.x += __shfl_xor(a0.x, 32, 64); a0.y += __shfl_xor(a0.y, 32, 64);
    a0.z += __shfl_xor(a0.z, 32, 64); a0.w += __shfl_xor(a0.w, 32, 64);

    if (lane < 16) ((float4*)(sums + (long)v * DIM))[sub] = a0;
}

// Rare path: overflow edges (deg > CAP) — adds fp32 rows into sums.
__global__ void spill_kernel(const float* __restrict__ verts,
                             const int* __restrict__ spill,
                             const int* __restrict__ nspill,
                             float* __restrict__ sums) {
    const int lane = threadIdx.x & 63;
    const int wave = (int)((blockIdx.x * blockDim.x + threadIdx.x) >> 6);
    const int nwaves = (int)((gridDim.x * blockDim.x) >> 6);
    int n = *nspill; if (n > SPILL_MAX) n = SPILL_MAX;
    for (int i = wave; i < n; i += nwaves) {
        const int t = spill[2 * i], nb = spill[2 * i + 1];
        atomicAdd(&sums[(long)t * DIM + lane], verts[(long)nb * DIM + lane]);
    }
}

// ---------------------------------------------------------------------------
// MFMA matvec: out[V,64] = A(V x 128) @ Bw(128 x 64) + b0 + deg*b1, where
// A = [x_bf16 | s_bf16], Bw = [W0^T; W1^T]. mfma_f32_16x16x32_bf16:
//   A-frag:  lane holds A[m = lane&15][k = quad*8 + j]
//   B-frag:  lane holds B[k = quad*8 + j][n = lane&15]  (mirror of A)
//   C/D:     lane holds D[row = quad*4 + reg][col = lane&15]
// One wave per 16-vertex tile; 16 B-frags hoisted (weights, L2-hot).
// ---------------------------------------------------------------------------
__global__ __launch_bounds__(256)
void matvec_mfma_kernel(const uint2* __restrict__ vbf,
                        const float* __restrict__ sums,
                        const float* __restrict__ w0,
                        const float* __restrict__ b0,
                        const float* __restrict__ w1,
                        const float* __restrict__ b1,
                        const int* __restrict__ cnt,
                        float* __restrict__ out) {
    const int lane = threadIdx.x & 63;
    const int quad = lane >> 4;
    const int n = lane & 15;
    const int wave = (int)((blockIdx.x * blockDim.x + threadIdx.x) >> 6);
    const int nwaves = (int)((gridDim.x * blockDim.x) >> 6);

    // Hoist 16 B-fragments: B[c][t], c = K-chunk (0,1: W0; 2,3: W1), t = col-tile.
    // B[k_g][n_g] = W[d = t*16+n][k = (c&1)*32 + quad*8 + j]  (y_d = sum_k W[d][k] A[k])
    short8 B[4][4];
#pragma unroll
    for (int c = 0; c < 4; ++c) {
        const float* wsrc = (c < 2) ? w0 : w1;
        const int kb = (c & 1) * 32 + quad * 8;
#pragma unroll
        for (int t = 0; t < 4; ++t) {
            const int d = t * 16 + n;
            const float4 p = *(const float4*)(wsrc + d * DIM + kb);
            const float4 q = *(const float4*)(wsrc + d * DIM + kb + 4);
            B[c][t] = pack_bf8(p, q);
        }
    }
    float bias0[4], bias1[4];
#pragma unroll
    for (int t = 0; t < 4; ++t) { bias0[t] = b0[t * 16 + n]; bias1[t] = b1[t * 16 + n]; }

    const short8* vb8 = (const short8*)vbf;    // 8 uint16 = 16 B per frag

    for (int tile = wave; tile < NTILE; tile += nwaves) {
        const int base = tile * 16;
        const long v = base + n;               // this lane's A row
        f32x4 acc[4] = {{0.f,0.f,0.f,0.f},{0.f,0.f,0.f,0.f},
                        {0.f,0.f,0.f,0.f},{0.f,0.f,0.f,0.f}};

        // K-chunks 0,1: x from vbf (already bf16; 16B aligned frag loads)
#pragma unroll
        for (int c = 0; c < 2; ++c) {
            const short8 A = vb8[v * 8 + c * 4 + quad];
#pragma unroll
            for (int t = 0; t < 4; ++t)
                acc[t] = __builtin_amdgcn_mfma_f32_16x16x32_bf16(A, B[c][t], acc[t], 0, 0, 0);
        }
        // K-chunks 2,3: s from fp32 sums, packed to bf16 in-flight
#pragma unroll
        for (int c = 2; c < 4; ++c) {
            const int kb = (c - 2) * 32 + quad * 8;
            const float4 p = *(const float4*)(sums + v * DIM + kb);
            const float4 q = *(const float4*)(sums + v * DIM + kb + 4);
            const short8 A = pack_bf8(p, q);
#pragma unroll
            for (int t = 0; t < 4; ++t)
                acc[t] = __builtin_amdgcn_mfma_f32_16x16x32_bf16(A, B[c][t], acc[t], 0, 0, 0);
        }
        // Epilogue: D[row=quad*4+reg][col=n] + b0[d] + deg*b1[d]
#pragma unroll
        for (int r = 0; r < 4; ++r) {
            const int row = base + quad * 4 + r;
            const float dg = (float)cnt[row];
#pragma unroll
            for (int t = 0; t < 4; ++t)
                out[(long)row * DIM + t * 16 + n] = acc[t][r] + fmaf(dg, bias1[t], bias0[t]);
        }
    }
}

// ==========================================================================

extern "C" void kernel_launch(void* const* d_in, const int* in_sizes, int n_in,
                              void* d_out, int out_size, void* d_ws, size_t ws_size,
                              hipStream_t stream) {
    const float* verts = (const float*)d_in[0];
    const int*   edges = (const int*)d_in[1];
    const float* w0_w  = (const float*)d_in[2];
    const float* w0_b  = (const float*)d_in[3];
    const float* w1_w  = (const float*)d_in[4];
    const float* w1_b  = (const float*)d_in[5];
    float* out = (float*)d_out;

    // Workspace: sums fp32 V*D | vbf bf16 V*D | col V*CAP | spill | cnt | misc
    char* p = (char*)d_ws;
    float* sums  = (float*)p;  p += (size_t)NV * DIM * 4;
    uint2* vbf   = (uint2*)p;  p += (size_t)NV * DIM * 2;
    int* col     = (int*)p;    p += (size_t)NV * CAP * 4;
    int* spill   = (int*)p;    p += (size_t)SPILL_MAX * 8;
    int* cnt     = (int*)p;    p += (size_t)NV * 4;
    int* nspill  = (int*)p;
    int* flag    = nspill + 1;

    hipMemsetAsync(cnt, 0, (size_t)NV * 4 + 8, stream);
    detect_kernel<<<1, 64, 0, stream>>>(edges, flag);
    prep_kernel<<<(NV * (DIM / 4) + 255) / 256, 256, 0, stream>>>(verts, vbf);
    // 2048 blocks = 8 partitions x 256-block sub-grids
    fill_kernel<<<2048, 256, 0, stream>>>(edges, cnt, col, spill, nspill, flag);
    gather_kernel<<<(NV + 3) / 4, 256, 0, stream>>>(vbf, cnt, col, sums);
    spill_kernel<<<64, 256, 0, stream>>>(verts, spill, nspill, sums);
    // 6250 tiles, one per wave: 1563 blocks x 4 waves (grid-stride guard)
    matvec_mfma_kernel<<<1563, 256, 0, stream>>>(vbf, sums, w0_w, w0_b,
                                                 w1_w, w1_b, cnt, out);
}